// Round 1
// baseline (1031.661 us; speedup 1.0000x reference)
//
#include <hip/hip_runtime.h>

#define HW 96
#define NPIX 9216      // 96*96
#define NCH 128
#define NB 16

// ---------------- channel mix: mixed[b,c,p] = sum_i lin[c,i] * x[b,i,p] ----------------
// block = 256 threads (4 waves), tile = 64 pixels x all 128 out-channels, one batch.
// x tile staged in LDS k-major (bank-conflict-free b32 reads, 2-way is free).
// Each wave: 32 channels in 4 groups of 8; lin reads are wave-uniform -> s_load.
template<int K>
__global__ __launch_bounds__(256) void mix_kernel(const float* __restrict__ x,
                                                  const float* __restrict__ lin,
                                                  float* __restrict__ mixed) {
    __shared__ float xs[K * 64];
    const int p0 = blockIdx.x * 64;
    const int b  = blockIdx.y;
    const int t  = threadIdx.x;
    const float* xb = x + (size_t)b * K * NPIX + p0;
    {
        const int p  = t & 63;
        const int k0 = t >> 6;          // 0..3
        #pragma unroll
        for (int k = k0; k < K; k += 4)
            xs[k * 64 + p] = xb[(size_t)k * NPIX + p];
    }
    __syncthreads();
    const int lane = t & 63;
    const int wv   = t >> 6;
    float* ob = mixed + (size_t)b * NCH * NPIX + p0 + lane;
    for (int cg = 0; cg < 4; ++cg) {
        const int c0 = __builtin_amdgcn_readfirstlane(wv * 32 + cg * 8);
        float acc[8];
        #pragma unroll
        for (int j = 0; j < 8; ++j) acc[j] = 0.f;
        #pragma unroll 4
        for (int k = 0; k < K; ++k) {
            const float xv = xs[k * 64 + lane];
            #pragma unroll
            for (int j = 0; j < 8; ++j)
                acc[j] = fmaf(lin[(c0 + j) * K + k], xv, acc[j]);
        }
        #pragma unroll
        for (int j = 0; j < 8; ++j)
            ob[(size_t)(c0 + j) * NPIX] = acc[j];
    }
}

// ---------------- bilinear affine sample ----------------
// ix = ((grid_x+1)*W - 1)*0.5 with grid_x = t0*gx + t1*gy + t2, gx=(w+.5)/48-1
//    = t0*w + t1*h + 48*t2 - 47.5*(t0+t1) + 47.5   (identity theta -> ix = w)
struct Taps { int i00, i01, i10, i11; float w00, w01, w10, w11; };

__device__ inline Taps make_taps(const float* __restrict__ th, int h, int w) {
    const float t0 = th[0], t1 = th[1], t2 = th[2];
    const float t3 = th[3], t4 = th[4], t5 = th[5];
    const float ix = t0 * w + t1 * h + (48.f * t2 - 47.5f * (t0 + t1) + 47.5f);
    const float iy = t3 * w + t4 * h + (48.f * t5 - 47.5f * (t3 + t4) + 47.5f);
    const float x0f = floorf(ix), y0f = floorf(iy);
    const float fx = ix - x0f, fy = iy - y0f;
    const int x0 = (int)x0f, y0 = (int)y0f;
    const int x1 = x0 + 1, y1 = y0 + 1;
    const float vx0 = (x0 >= 0 && x0 < HW) ? 1.f : 0.f;
    const float vx1 = (x1 >= 0 && x1 < HW) ? 1.f : 0.f;
    const float vy0 = (y0 >= 0 && y0 < HW) ? 1.f : 0.f;
    const float vy1 = (y1 >= 0 && y1 < HW) ? 1.f : 0.f;
    const int x0c = min(max(x0, 0), HW - 1), x1c = min(max(x1, 0), HW - 1);
    const int y0c = min(max(y0, 0), HW - 1), y1c = min(max(y1, 0), HW - 1);
    Taps tp;
    tp.w00 = (1.f - fy) * (1.f - fx) * vy0 * vx0;
    tp.w01 = (1.f - fy) * fx * vy0 * vx1;
    tp.w10 = fy * (1.f - fx) * vy1 * vx0;
    tp.w11 = fy * fx * vy1 * vx1;
    tp.i00 = y0c * HW + x0c;  tp.i01 = y0c * HW + x1c;
    tp.i10 = y1c * HW + x0c;  tp.i11 = y1c * HW + x1c;
    return tp;
}

// block = 192 threads = 2 rows of 96; grid = (C, H/2). Tap geometry computed once,
// reused for all 16 batches (theta is batch-independent). Residual read/write is the
// same element -> safe in-place on `out`.
template<bool RES>
__global__ __launch_bounds__(192) void sample_kernel(const float* __restrict__ mixed,
                                                     const float* __restrict__ geo,
                                                     const float* __restrict__ box,
                                                     float* __restrict__ out) {
    const int c  = blockIdx.x;
    const int lh = threadIdx.x / 96;
    const int w  = threadIdx.x - lh * 96;
    const int h  = blockIdx.y * 2 + lh;
    const Taps g  = make_taps(geo + c * 6, h, w);
    const Taps bx = make_taps(box + c * 6, h, w);
    const float bw = bx.w00 + bx.w01 + bx.w10 + bx.w11;   // box-sample of ones
    const float* m = mixed + (size_t)c * NPIX;
    float* o = out + (size_t)c * NPIX + h * HW + w;
    #pragma unroll 4
    for (int b = 0; b < NB; ++b) {
        float v = g.w00 * m[g.i00] + g.w01 * m[g.i01]
                + g.w10 * m[g.i10] + g.w11 * m[g.i11];
        v *= bw;
        if (RES) v += *o;
        *o = v;
        m += (size_t)NCH * NPIX;
        o += (size_t)NCH * NPIX;
    }
}

// ---------------- mean pool over H,W ----------------
__global__ __launch_bounds__(256) void pool_kernel(const float* __restrict__ feat,
                                                   float* __restrict__ pooled) {
    const int bc = blockIdx.x;           // b*128 + c
    const float* f = feat + (size_t)bc * NPIX;
    float s = 0.f;
    for (int i = threadIdx.x; i < NPIX; i += 256) s += f[i];
    #pragma unroll
    for (int off = 32; off > 0; off >>= 1) s += __shfl_down(s, off, 64);
    __shared__ float red[4];
    if ((threadIdx.x & 63) == 0) red[threadIdx.x >> 6] = s;
    __syncthreads();
    if (threadIdx.x == 0)
        pooled[bc] = (red[0] + red[1] + red[2] + red[3]) * (1.f / (float)NPIX);
}

// ---------------- dense: logits[b,n] = pooled[b,:] . W[n,:] + bias[n] ----------------
__global__ __launch_bounds__(256) void dense_kernel(const float* __restrict__ pooled,
                                                    const float* __restrict__ Wt,
                                                    const float* __restrict__ bias,
                                                    float* __restrict__ out) {
    const int idx = blockIdx.x * 256 + threadIdx.x;
    if (idx >= NB * 1000) return;
    const int b = idx / 1000, n = idx - b * 1000;
    float acc = bias[n];
    const float* p = pooled + b * NCH;
    const float* wr = Wt + n * NCH;
    #pragma unroll 4
    for (int c = 0; c < NCH; ++c) acc = fmaf(p[c], wr[c], acc);
    out[idx] = acc;
}

extern "C" void kernel_launch(void* const* d_in, const int* in_sizes, int n_in,
                              void* d_out, int out_size, void* d_ws, size_t ws_size,
                              hipStream_t stream) {
    const float* x       = (const float*)d_in[0];   // [16,64,96,96]
    const float* in_geo  = (const float*)d_in[1];   // [128,2,3]
    const float* in_box  = (const float*)d_in[2];   // [128,2,3]
    const float* in_lin  = (const float*)d_in[3];   // [128,64]
    const float* lay_geo = (const float*)d_in[4];   // [4,128,2,3]
    const float* lay_box = (const float*)d_in[5];   // [4,128,2,3]
    const float* lay_lin = (const float*)d_in[6];   // [4,128,128]
    const float* dense_w = (const float*)d_in[7];   // [1000,128]
    const float* dense_b = (const float*)d_in[8];   // [1000]

    float* out  = (float*)d_out;
    float* feat = out + NB * 1000;                  // [16,128,96,96] lives in d_out
    float* mixed  = (float*)d_ws;                   // 75.5 MB scratch
    float* pooled = (float*)d_ws;                   // reused after mixed is dead

    const dim3 mixGrid(NPIX / 64, NB);
    const dim3 smpGrid(NCH, HW / 2);

    mix_kernel<64><<<mixGrid, 256, 0, stream>>>(x, in_lin, mixed);
    sample_kernel<false><<<smpGrid, 192, 0, stream>>>(mixed, in_geo, in_box, feat);
    for (int i = 0; i < 4; ++i) {
        mix_kernel<128><<<mixGrid, 256, 0, stream>>>(feat, lay_lin + i * NCH * NCH, mixed);
        sample_kernel<true><<<smpGrid, 192, 0, stream>>>(mixed, lay_geo + i * NCH * 6,
                                                         lay_box + i * NCH * 6, feat);
    }
    pool_kernel<<<NB * NCH, 256, 0, stream>>>(feat, pooled);
    dense_kernel<<<(NB * 1000 + 255) / 256, 256, 0, stream>>>(pooled, dense_w, dense_b, out);
}

// Round 2
// 706.052 us; speedup vs baseline: 1.4612x; 1.4612x over previous
//
#include <hip/hip_runtime.h>

#define HW 96
#define NPIX 9216      // 96*96
#define NCH 128
#define NB 16

// ---------------- channel mix: mixed[b,c,p] = sum_i lin[c,i] * x[b,i,p] ----------------
// Register-tiled GEMM: block = 256 threads, tile = 128 px x 128 ch, K chunked by 32.
// Both operands staged in LDS (lin transposed at staging, pad 132 keeps writes <=4-way
// and reads 16B-aligned b128 broadcasts). No scalar loads in the FMA loop.
template<int K>
__global__ __launch_bounds__(256, 4) void mix_kernel(const float* __restrict__ x,
                                                     const float* __restrict__ lin,
                                                     float* __restrict__ mixed) {
    constexpr int KC  = 32;
    constexpr int LSP = 132;                 // padded ls row stride (16B-aligned b128 reads)
    __shared__ float xs[KC * 128];
    __shared__ float ls[KC * LSP];
    const int p0 = blockIdx.x * 128;
    const int b  = blockIdx.y;
    const int t  = threadIdx.x;
    const int pg = t & 31;                   // 4-pixel group
    const int cg = t >> 5;                   // 16-channel group
    const float* xb = x + (size_t)b * K * NPIX + p0;

    float acc[4][16];
    #pragma unroll
    for (int i = 0; i < 4; ++i)
        #pragma unroll
        for (int j = 0; j < 16; ++j) acc[i][j] = 0.f;

    const int sc = t >> 3;                   // staging channel row (0..31 per pass)
    const int sq = t & 7;                    // float4 index within 32-float k chunk

    for (int k0 = 0; k0 < K; k0 += KC) {
        __syncthreads();
        // xs[kk][pp] = x[b][k0+kk][p0+pp]  (coalesced float4 copy)
        #pragma unroll
        for (int r = 0; r < 4; ++r) {
            const int flat = r * 1024 + t * 4;
            const int kk = flat >> 7, pp = flat & 127;
            *(float4*)&xs[kk * 128 + pp] =
                *(const float4*)&xb[(size_t)(k0 + kk) * NPIX + pp];
        }
        // ls[kk][c] = lin[c][k0+kk]  (coalesced read, transposing LDS write)
        #pragma unroll
        for (int p = 0; p < 4; ++p) {
            const int c = p * 32 + sc;
            const float4 v = *(const float4*)&lin[c * K + k0 + 4 * sq];
            ls[(4 * sq + 0) * LSP + c] = v.x;
            ls[(4 * sq + 1) * LSP + c] = v.y;
            ls[(4 * sq + 2) * LSP + c] = v.z;
            ls[(4 * sq + 3) * LSP + c] = v.w;
        }
        __syncthreads();
        #pragma unroll 2
        for (int kk = 0; kk < KC; ++kk) {
            const float4 xv = *(const float4*)&xs[kk * 128 + 4 * pg];
            const float* lr = &ls[kk * LSP + 16 * cg];
            float lv[16];
            #pragma unroll
            for (int j = 0; j < 16; ++j) lv[j] = lr[j];
            #pragma unroll
            for (int j = 0; j < 16; ++j) {
                acc[0][j] = fmaf(xv.x, lv[j], acc[0][j]);
                acc[1][j] = fmaf(xv.y, lv[j], acc[1][j]);
                acc[2][j] = fmaf(xv.z, lv[j], acc[2][j]);
                acc[3][j] = fmaf(xv.w, lv[j], acc[3][j]);
            }
        }
    }
    float* ob = mixed + (size_t)b * NCH * NPIX + p0 + 4 * pg;
    #pragma unroll
    for (int j = 0; j < 16; ++j) {
        float4 v = { acc[0][j], acc[1][j], acc[2][j], acc[3][j] };
        *(float4*)&ob[(size_t)(16 * cg + j) * NPIX] = v;
    }
}

// ---------------- bilinear affine sample ----------------
// ix = t0*w + t1*h + 48*t2 - 47.5*(t0+t1) + 47.5   (identity theta -> ix = w)
struct Taps { int i00, i01, i10, i11; float w00, w01, w10, w11; };

__device__ inline Taps make_taps(const float* __restrict__ th, int h, int w) {
    const float t0 = th[0], t1 = th[1], t2 = th[2];
    const float t3 = th[3], t4 = th[4], t5 = th[5];
    const float ix = t0 * w + t1 * h + (48.f * t2 - 47.5f * (t0 + t1) + 47.5f);
    const float iy = t3 * w + t4 * h + (48.f * t5 - 47.5f * (t3 + t4) + 47.5f);
    const float x0f = floorf(ix), y0f = floorf(iy);
    const float fx = ix - x0f, fy = iy - y0f;
    const int x0 = (int)x0f, y0 = (int)y0f;
    const int x1 = x0 + 1, y1 = y0 + 1;
    const float vx0 = (x0 >= 0 && x0 < HW) ? 1.f : 0.f;
    const float vx1 = (x1 >= 0 && x1 < HW) ? 1.f : 0.f;
    const float vy0 = (y0 >= 0 && y0 < HW) ? 1.f : 0.f;
    const float vy1 = (y1 >= 0 && y1 < HW) ? 1.f : 0.f;
    const int x0c = min(max(x0, 0), HW - 1), x1c = min(max(x1, 0), HW - 1);
    const int y0c = min(max(y0, 0), HW - 1), y1c = min(max(y1, 0), HW - 1);
    Taps tp;
    tp.w00 = (1.f - fy) * (1.f - fx) * vy0 * vx0;
    tp.w01 = (1.f - fy) * fx * vy0 * vx1;
    tp.w10 = fy * (1.f - fx) * vy1 * vx0;
    tp.w11 = fy * fx * vy1 * vx1;
    tp.i00 = y0c * HW + x0c;  tp.i01 = y0c * HW + x1c;
    tp.i10 = y1c * HW + x0c;  tp.i11 = y1c * HW + x1c;
    return tp;
}

// block = 192 threads = 2 rows; grid = (C, H/2). Taps computed once, reused over all
// 16 batches (theta batch-independent). In-place residual is element-exact safe.
template<bool RES>
__global__ __launch_bounds__(192) void sample_kernel(const float* __restrict__ mixed,
                                                     const float* __restrict__ geo,
                                                     const float* __restrict__ box,
                                                     float* __restrict__ out) {
    const int c  = blockIdx.x;
    const int lh = threadIdx.x / 96;
    const int w  = threadIdx.x - lh * 96;
    const int h  = blockIdx.y * 2 + lh;
    const Taps g  = make_taps(geo + c * 6, h, w);
    const Taps bx = make_taps(box + c * 6, h, w);
    const float bw = bx.w00 + bx.w01 + bx.w10 + bx.w11;   // box-sample of ones
    const float* m = mixed + (size_t)c * NPIX;
    float* o = out + (size_t)c * NPIX + h * HW + w;
    #pragma unroll 8
    for (int b = 0; b < NB; ++b) {
        float v = g.w00 * m[g.i00] + g.w01 * m[g.i01]
                + g.w10 * m[g.i10] + g.w11 * m[g.i11];
        v *= bw;
        if (RES) v += *o;
        *o = v;
        m += (size_t)NCH * NPIX;
        o += (size_t)NCH * NPIX;
    }
}

// ---------------- mean pool over H,W ----------------
__global__ __launch_bounds__(256) void pool_kernel(const float* __restrict__ feat,
                                                   float* __restrict__ pooled) {
    const int bc = blockIdx.x;           // b*128 + c
    const float4* f = (const float4*)(feat + (size_t)bc * NPIX);
    float s = 0.f;
    for (int i = threadIdx.x; i < NPIX / 4; i += 256) {
        const float4 v = f[i];
        s += (v.x + v.y) + (v.z + v.w);
    }
    #pragma unroll
    for (int off = 32; off > 0; off >>= 1) s += __shfl_down(s, off, 64);
    __shared__ float red[4];
    if ((threadIdx.x & 63) == 0) red[threadIdx.x >> 6] = s;
    __syncthreads();
    if (threadIdx.x == 0)
        pooled[bc] = (red[0] + red[1] + red[2] + red[3]) * (1.f / (float)NPIX);
}

// ---------------- dense: logits[b,n] = pooled[b,:] . W[n,:] + bias[n] ----------------
__global__ __launch_bounds__(256) void dense_kernel(const float* __restrict__ pooled,
                                                    const float* __restrict__ Wt,
                                                    const float* __restrict__ bias,
                                                    float* __restrict__ out) {
    const int idx = blockIdx.x * 256 + threadIdx.x;
    if (idx >= NB * 1000) return;
    const int b = idx / 1000, n = idx - b * 1000;
    float acc = bias[n];
    const float* p = pooled + b * NCH;
    const float* wr = Wt + n * NCH;
    #pragma unroll 4
    for (int c = 0; c < NCH; ++c) acc = fmaf(p[c], wr[c], acc);
    out[idx] = acc;
}

extern "C" void kernel_launch(void* const* d_in, const int* in_sizes, int n_in,
                              void* d_out, int out_size, void* d_ws, size_t ws_size,
                              hipStream_t stream) {
    const float* x       = (const float*)d_in[0];   // [16,64,96,96]
    const float* in_geo  = (const float*)d_in[1];   // [128,2,3]
    const float* in_box  = (const float*)d_in[2];   // [128,2,3]
    const float* in_lin  = (const float*)d_in[3];   // [128,64]
    const float* lay_geo = (const float*)d_in[4];   // [4,128,2,3]
    const float* lay_box = (const float*)d_in[5];   // [4,128,2,3]
    const float* lay_lin = (const float*)d_in[6];   // [4,128,128]
    const float* dense_w = (const float*)d_in[7];   // [1000,128]
    const float* dense_b = (const float*)d_in[8];   // [1000]

    float* out  = (float*)d_out;
    float* feat = out + NB * 1000;                  // [16,128,96,96] lives in d_out
    float* mixed  = (float*)d_ws;                   // 75.5 MB scratch
    float* pooled = (float*)d_ws;                   // reused after mixed is dead

    const dim3 mixGrid(NPIX / 128, NB);
    const dim3 smpGrid(NCH, HW / 2);

    mix_kernel<64><<<mixGrid, 256, 0, stream>>>(x, in_lin, mixed);
    sample_kernel<false><<<smpGrid, 192, 0, stream>>>(mixed, in_geo, in_box, feat);
    for (int i = 0; i < 4; ++i) {
        mix_kernel<128><<<mixGrid, 256, 0, stream>>>(feat, lay_lin + i * NCH * NCH, mixed);
        sample_kernel<true><<<smpGrid, 192, 0, stream>>>(mixed, lay_geo + i * NCH * 6,
                                                         lay_box + i * NCH * 6, feat);
    }
    pool_kernel<<<NB * NCH, 256, 0, stream>>>(feat, pooled);
    dense_kernel<<<(NB * 1000 + 255) / 256, 256, 0, stream>>>(pooled, dense_w, dense_b, out);
}

// Round 3
// 687.402 us; speedup vs baseline: 1.5008x; 1.0271x over previous
//
#include <hip/hip_runtime.h>

#define HW 96
#define NPIX 9216      // 96*96
#define NCH 128
#define NB 16

// ---------------- channel mix: mixed[b,c,p] = sum_i lin[c,i] * x[b,i,p] ----------------
// Register-tiled GEMM. Block = 128 threads, tile = 128 px x 128 ch, per-thread
// acc = 8 px x 16 ch (128 VGPRs). Per kk-step: 128 FMA per 6 ds_read_b128 ->
// LDS pipe (shared per CU) ~balanced with FMA pipes at 4 blocks/CU (round-2
// counters showed 4px x 16ch was 1.9x LDS-oversubscribed -> VALUBusy 51%).
template<int K>
__global__ __launch_bounds__(128, 2) void mix_kernel(const float* __restrict__ x,
                                                     const float* __restrict__ lin,
                                                     float* __restrict__ mixed) {
    constexpr int KC  = 32;
    constexpr int LSP = 132;                 // padded ls row stride
    __shared__ float xs[KC * 128];
    __shared__ float ls[KC * LSP];
    const int p0 = blockIdx.x * 128;
    const int b  = blockIdx.y;
    const int t  = threadIdx.x;
    const int pg = t & 15;                   // 8-pixel group
    const int cg = t >> 4;                   // 16-channel group (0..7)
    const float* xb = x + (size_t)b * K * NPIX + p0;

    float acc[8][16];
    #pragma unroll
    for (int i = 0; i < 8; ++i)
        #pragma unroll
        for (int j = 0; j < 16; ++j) acc[i][j] = 0.f;

    for (int k0 = 0; k0 < K; k0 += KC) {
        __syncthreads();
        // xs[kk][pp] = x[b][k0+kk][p0+pp]  (coalesced float4)
        #pragma unroll
        for (int r = 0; r < 8; ++r) {
            const int flat = r * 512 + t * 4;
            const int kk = flat >> 7, pp = flat & 127;
            *(float4*)&xs[kk * 128 + pp] =
                *(const float4*)&xb[(size_t)(k0 + kk) * NPIX + pp];
        }
        // ls[kk][c] = lin[c][k0+kk]; strided global read (lin is L2-resident, 64KB),
        // LDS write bank = (4*row + c) % 32 -> 2-way across 64 lanes (free).
        #pragma unroll
        for (int r = 0; r < KC / 4; ++r) {
            const float4 v = *(const float4*)&lin[t * K + k0 + 4 * r];
            ls[(4 * r + 0) * LSP + t] = v.x;
            ls[(4 * r + 1) * LSP + t] = v.y;
            ls[(4 * r + 2) * LSP + t] = v.z;
            ls[(4 * r + 3) * LSP + t] = v.w;
        }
        __syncthreads();
        #pragma unroll 2
        for (int kk = 0; kk < KC; ++kk) {
            const float4 xa = *(const float4*)&xs[kk * 128 + 8 * pg];
            const float4 xc = *(const float4*)&xs[kk * 128 + 8 * pg + 4];
            const float* lr = &ls[kk * LSP + 16 * cg];
            float lv[16];
            #pragma unroll
            for (int j = 0; j < 16; ++j) lv[j] = lr[j];
            #pragma unroll
            for (int j = 0; j < 16; ++j) {
                acc[0][j] = fmaf(xa.x, lv[j], acc[0][j]);
                acc[1][j] = fmaf(xa.y, lv[j], acc[1][j]);
                acc[2][j] = fmaf(xa.z, lv[j], acc[2][j]);
                acc[3][j] = fmaf(xa.w, lv[j], acc[3][j]);
                acc[4][j] = fmaf(xc.x, lv[j], acc[4][j]);
                acc[5][j] = fmaf(xc.y, lv[j], acc[5][j]);
                acc[6][j] = fmaf(xc.z, lv[j], acc[6][j]);
                acc[7][j] = fmaf(xc.w, lv[j], acc[7][j]);
            }
        }
    }
    float* ob = mixed + (size_t)b * NCH * NPIX + p0 + 8 * pg;
    #pragma unroll
    for (int j = 0; j < 16; ++j) {
        float* orow = ob + (size_t)(16 * cg + j) * NPIX;
        float4 v0 = { acc[0][j], acc[1][j], acc[2][j], acc[3][j] };
        float4 v1 = { acc[4][j], acc[5][j], acc[6][j], acc[7][j] };
        *(float4*)&orow[0] = v0;
        *(float4*)&orow[4] = v1;
    }
}

// ---------------- bilinear affine sample ----------------
// ix = t0*w + t1*h + 48*t2 - 47.5*(t0+t1) + 47.5   (identity theta -> ix = w)
struct Taps { int i00, i01, i10, i11; float w00, w01, w10, w11; };

__device__ inline Taps make_taps(const float* __restrict__ th, int h, int w) {
    const float t0 = th[0], t1 = th[1], t2 = th[2];
    const float t3 = th[3], t4 = th[4], t5 = th[5];
    const float ix = t0 * w + t1 * h + (48.f * t2 - 47.5f * (t0 + t1) + 47.5f);
    const float iy = t3 * w + t4 * h + (48.f * t5 - 47.5f * (t3 + t4) + 47.5f);
    const float x0f = floorf(ix), y0f = floorf(iy);
    const float fx = ix - x0f, fy = iy - y0f;
    const int x0 = (int)x0f, y0 = (int)y0f;
    const int x1 = x0 + 1, y1 = y0 + 1;
    const float vx0 = (x0 >= 0 && x0 < HW) ? 1.f : 0.f;
    const float vx1 = (x1 >= 0 && x1 < HW) ? 1.f : 0.f;
    const float vy0 = (y0 >= 0 && y0 < HW) ? 1.f : 0.f;
    const float vy1 = (y1 >= 0 && y1 < HW) ? 1.f : 0.f;
    const int x0c = min(max(x0, 0), HW - 1), x1c = min(max(x1, 0), HW - 1);
    const int y0c = min(max(y0, 0), HW - 1), y1c = min(max(y1, 0), HW - 1);
    Taps tp;
    tp.w00 = (1.f - fy) * (1.f - fx) * vy0 * vx0;
    tp.w01 = (1.f - fy) * fx * vy0 * vx1;
    tp.w10 = fy * (1.f - fx) * vy1 * vx0;
    tp.w11 = fy * fx * vy1 * vx1;
    tp.i00 = y0c * HW + x0c;  tp.i01 = y0c * HW + x1c;
    tp.i10 = y1c * HW + x0c;  tp.i11 = y1c * HW + x1c;
    return tp;
}

// LDS-staged sample: block = (channel c, batch b); whole 36KB channel plane of
// `mixed` staged into LDS (coalesced), 4-tap gathers hit LDS instead of L1/L2.
// Global read/write fully coalesced. In-place residual is element-exact safe.
template<bool RES>
__global__ __launch_bounds__(256) void sample_kernel(const float* __restrict__ mixed,
                                                     const float* __restrict__ geo,
                                                     const float* __restrict__ box,
                                                     float* __restrict__ out) {
    __shared__ float m[NPIX];
    const int c = blockIdx.x;
    const int b = blockIdx.y;
    const int t = threadIdx.x;
    const float* src = mixed + ((size_t)b * NCH + c) * NPIX;
    #pragma unroll
    for (int i = 0; i < 9; ++i)
        *(float4*)&m[i * 1024 + t * 4] = *(const float4*)&src[i * 1024 + t * 4];
    const float* gth = geo + c * 6;
    const float* bth = box + c * 6;
    float* o = out + ((size_t)b * NCH + c) * NPIX;
    __syncthreads();
    #pragma unroll 4
    for (int r = 0; r < NPIX / 256; ++r) {
        const int p = r * 256 + t;
        const int h = p / 96;
        const int w = p - h * 96;
        const Taps g  = make_taps(gth, h, w);
        const Taps bx = make_taps(bth, h, w);
        const float bw = bx.w00 + bx.w01 + bx.w10 + bx.w11;   // box-sample of ones
        float v = g.w00 * m[g.i00] + g.w01 * m[g.i01]
                + g.w10 * m[g.i10] + g.w11 * m[g.i11];
        v *= bw;
        if (RES) v += o[p];
        o[p] = v;
    }
}

// ---------------- mean pool over H,W ----------------
__global__ __launch_bounds__(256) void pool_kernel(const float* __restrict__ feat,
                                                   float* __restrict__ pooled) {
    const int bc = blockIdx.x;           // b*128 + c
    const float4* f = (const float4*)(feat + (size_t)bc * NPIX);
    float s = 0.f;
    for (int i = threadIdx.x; i < NPIX / 4; i += 256) {
        const float4 v = f[i];
        s += (v.x + v.y) + (v.z + v.w);
    }
    #pragma unroll
    for (int off = 32; off > 0; off >>= 1) s += __shfl_down(s, off, 64);
    __shared__ float red[4];
    if ((threadIdx.x & 63) == 0) red[threadIdx.x >> 6] = s;
    __syncthreads();
    if (threadIdx.x == 0)
        pooled[bc] = (red[0] + red[1] + red[2] + red[3]) * (1.f / (float)NPIX);
}

// ---------------- dense: logits[b,n] = pooled[b,:] . W[n,:] + bias[n] ----------------
__global__ __launch_bounds__(256) void dense_kernel(const float* __restrict__ pooled,
                                                    const float* __restrict__ Wt,
                                                    const float* __restrict__ bias,
                                                    float* __restrict__ out) {
    const int idx = blockIdx.x * 256 + threadIdx.x;
    if (idx >= NB * 1000) return;
    const int b = idx / 1000, n = idx - b * 1000;
    float acc = bias[n];
    const float* p = pooled + b * NCH;
    const float* wr = Wt + n * NCH;
    #pragma unroll 4
    for (int c = 0; c < NCH; ++c) acc = fmaf(p[c], wr[c], acc);
    out[idx] = acc;
}

extern "C" void kernel_launch(void* const* d_in, const int* in_sizes, int n_in,
                              void* d_out, int out_size, void* d_ws, size_t ws_size,
                              hipStream_t stream) {
    const float* x       = (const float*)d_in[0];   // [16,64,96,96]
    const float* in_geo  = (const float*)d_in[1];   // [128,2,3]
    const float* in_box  = (const float*)d_in[2];   // [128,2,3]
    const float* in_lin  = (const float*)d_in[3];   // [128,64]
    const float* lay_geo = (const float*)d_in[4];   // [4,128,2,3]
    const float* lay_box = (const float*)d_in[5];   // [4,128,2,3]
    const float* lay_lin = (const float*)d_in[6];   // [4,128,128]
    const float* dense_w = (const float*)d_in[7];   // [1000,128]
    const float* dense_b = (const float*)d_in[8];   // [1000]

    float* out  = (float*)d_out;
    float* feat = out + NB * 1000;                  // [16,128,96,96] lives in d_out
    float* mixed  = (float*)d_ws;                   // 75.5 MB scratch
    float* pooled = (float*)d_ws;                   // reused after mixed is dead

    const dim3 mixGrid(NPIX / 128, NB);
    const dim3 smpGrid(NCH, NB);

    mix_kernel<64><<<mixGrid, 128, 0, stream>>>(x, in_lin, mixed);
    sample_kernel<false><<<smpGrid, 256, 0, stream>>>(mixed, in_geo, in_box, feat);
    for (int i = 0; i < 4; ++i) {
        mix_kernel<128><<<mixGrid, 128, 0, stream>>>(feat, lay_lin + i * NCH * NCH, mixed);
        sample_kernel<true><<<smpGrid, 256, 0, stream>>>(mixed, lay_geo + i * NCH * 6,
                                                         lay_box + i * NCH * 6, feat);
    }
    pool_kernel<<<NB * NCH, 256, 0, stream>>>(feat, pooled);
    dense_kernel<<<(NB * 1000 + 255) / 256, 256, 0, stream>>>(pooled, dense_w, dense_b, out);
}